// Round 22
// baseline (4357.338 us; speedup 1.0000x reference)
//
#include <hip/hip_runtime.h>
#include <hip/hip_bf16.h>
#include <math.h>

#define H 1024
#define SEQ 2048
#define NTOK 4096
#define NE 64
#define AR 4    // q-rows per attn block
#define KVP 133 // padded K/V row stride (133 mod 32 = 5, coprime -> 2-way max)
#define KC 384  // OpenBLAS sgemm k-blocking (HASWELL/ZEN SGEMM_DEFAULT_Q)

// ---------------- numpy-emulation helpers ----------------
// numpy f32 exp: Cephes-based FMA SIMD kernel (loops_exponent_log)
__device__ __forceinline__ float np_expf(float x) {
  const float LOG2EF = 1.44269504088896341f;
  const float C1 = 0.693359375f;
  const float C2 = -2.12194440e-4f;
  float q = rintf(__fmul_rn(x, LOG2EF));
  float r = __fmaf_rn(q, -C1, x);
  r = __fmaf_rn(q, -C2, r);
  float p = 1.9875691500E-4f;
  p = __fmaf_rn(p, r, 1.3981999507E-3f);
  p = __fmaf_rn(p, r, 8.3334519073E-3f);
  p = __fmaf_rn(p, r, 4.1665795894E-2f);
  p = __fmaf_rn(p, r, 1.6666665459E-1f);
  p = __fmaf_rn(p, r, 5.0000001201E-1f);
  float r2 = __fmul_rn(r, r);
  float y = __fmaf_rn(p, r2, r);
  y = __fadd_rn(y, 1.0f);
  y = ldexpf(y, (int)q);
  if (x < -87.3365f) y = 0.0f;
  return y;
}

// numpy pairwise_sum SIMD block: 4 vector accs x 4 lanes
__device__ __forceinline__ float pw128_simd(const float* a) {
  float r[16];
#pragma unroll
  for (int i = 0; i < 16; ++i) r[i] = a[i];
#pragma unroll
  for (int m = 1; m < 8; ++m)
#pragma unroll
    for (int i = 0; i < 16; ++i) r[i] = __fadd_rn(r[i], a[m * 16 + i]);
  float V[4];
#pragma unroll
  for (int l = 0; l < 4; ++l)
    V[l] = __fadd_rn(__fadd_rn(r[l], r[4 + l]), __fadd_rn(r[8 + l], r[12 + l]));
  return __fadd_rn(__fadd_rn(V[0], V[2]), __fadd_rn(V[1], V[3]));
}
__device__ __forceinline__ float pw64_simd(const float* a) {
  float r[16];
#pragma unroll
  for (int i = 0; i < 16; ++i) r[i] = a[i];
#pragma unroll
  for (int m = 1; m < 4; ++m)
#pragma unroll
    for (int i = 0; i < 16; ++i) r[i] = __fadd_rn(r[i], a[m * 16 + i]);
  float V[4];
#pragma unroll
  for (int l = 0; l < 4; ++l)
    V[l] = __fadd_rn(__fadd_rn(r[l], r[4 + l]), __fadd_rn(r[8 + l], r[12 + l]));
  return __fadd_rn(__fadd_rn(V[0], V[2]), __fadd_rn(V[1], V[3]));
}
__device__ __forceinline__ float pw1024_simd(const float* a) {
  float B[8];
#pragma unroll
  for (int i = 0; i < 8; ++i) B[i] = pw128_simd(a + i * 128);
  return __fadd_rn(__fadd_rn(__fadd_rn(B[0], B[1]), __fadd_rn(B[2], B[3])),
                   __fadd_rn(__fadd_rn(B[4], B[5]), __fadd_rn(B[6], B[7])));
}
__device__ __forceinline__ double wave_sum64d(double v) {
#pragma unroll
  for (int m = 32; m >= 1; m >>= 1) v += __shfl_xor(v, m);
  return v;
}

// ---------------- numpy argsort (introsort) — verbatim port ----------------
__device__ void np_aheapsort(const float* v, int* tosort, int off, int n) {
  int* a = tosort + off - 1;  // 1-based
  for (int l = n >> 1; l > 0; --l) {
    int tmp = a[l];
    int i = l, j = l << 1;
    while (j <= n) {
      if (j < n && v[a[j]] < v[a[j + 1]]) j += 1;
      if (v[tmp] < v[a[j]]) {
        a[i] = a[j];
        i = j;
        j += j;
      } else
        break;
    }
    a[i] = tmp;
  }
  for (int m = n; m > 1;) {
    int tmp = a[m];
    a[m] = a[1];
    m -= 1;
    int i = 1, j = 2;
    while (j <= m) {
      if (j < m && v[a[j]] < v[a[j + 1]]) j++;
      if (v[tmp] < v[a[j]]) {
        a[i] = a[j];
        i = j;
        j += j;
      } else
        break;
    }
    a[i] = tmp;
  }
}

__device__ void np_aquicksort64(const float* v, int* t) {
  int stk[40];
  int sp = 0;
  int pl = 0, pr = 63;
  int depth_limit = 12;
  for (;;) {
    while ((pr - pl) > 15) {
      if (depth_limit-- < 0) {
        np_aheapsort(v, t, pl, pr - pl + 1);
        goto stack_pop;
      }
      int pm = pl + ((pr - pl) >> 1);
      if (v[t[pm]] < v[t[pl]]) {
        int x = t[pm];
        t[pm] = t[pl];
        t[pl] = x;
      }
      if (v[t[pr]] < v[t[pm]]) {
        int x = t[pr];
        t[pr] = t[pm];
        t[pm] = x;
      }
      if (v[t[pm]] < v[t[pl]]) {
        int x = t[pm];
        t[pm] = t[pl];
        t[pl] = x;
      }
      float vp = v[t[pm]];
      int pi = pl;
      int pj = pr - 1;
      {
        int x = t[pm];
        t[pm] = t[pj];
        t[pj] = x;
      }
      for (;;) {
        do ++pi;
        while (v[t[pi]] < vp);
        do --pj;
        while (vp < v[t[pj]]);
        if (pi >= pj) break;
        int x = t[pi];
        t[pi] = t[pj];
        t[pj] = x;
      }
      {
        int pk = pr - 1;
        int x = t[pi];
        t[pi] = t[pk];
        t[pk] = x;
      }
      if (pi - pl < pr - pi) {
        stk[sp++] = pi + 1;
        stk[sp++] = pr;
        pr = pi - 1;
      } else {
        stk[sp++] = pl;
        stk[sp++] = pi - 1;
        pl = pi + 1;
      }
    }
    for (int pi2 = pl + 1; pi2 <= pr; ++pi2) {
      int vi = t[pi2];
      float vpp = v[vi];
      int pj2 = pi2, pk2 = pi2 - 1;
      while (pj2 > pl && vpp < v[t[pk2]]) {
        t[pj2--] = t[pk2--];
      }
      t[pj2] = vi;
    }
  stack_pop:
    if (sp == 0) break;
    pr = stk[--sp];
    pl = stk[--sp];
  }
}

__global__ void zero_kernel(float* p, int n) {
  int i = blockIdx.x * blockDim.x + threadIdx.x;
  if (i < n) p[i] = 0.f;
}

// ---------------- LayerNorm + top router ----------------
__global__ __launch_bounds__(256) void ln_top_kernel(
    const float* __restrict__ x, const float* __restrict__ g,
    const float* __restrict__ be, const float* __restrict__ top_w,
    const float* __restrict__ top_b, float* __restrict__ xn,
    float* __restrict__ topp) {
  __shared__ float xr[4][1024];
  __shared__ float sq[4][1024];
  __shared__ float gb[1024], bb[1024];
  __shared__ float mubuf[4], invbuf[4];
  __shared__ float lbuf[4][2];
  const int t = threadIdx.x;
  const int tok0 = blockIdx.x * 4;
  for (int i = t; i < 1024; i += 256) {
    gb[i] = g[i];
    bb[i] = be[i];
  }
  for (int tk = 0; tk < 4; ++tk)
    for (int i = t; i < 1024; i += 256)
      xr[tk][i] = x[(size_t)(tok0 + tk) * H + i];
  __syncthreads();
  if (t < 4) mubuf[t] = __fdiv_rn(pw1024_simd(xr[t]), 1024.0f);
  __syncthreads();
  for (int tk = 0; tk < 4; ++tk) {
    const float mu = mubuf[tk];
    for (int i = t; i < 1024; i += 256) {
      float d = __fsub_rn(xr[tk][i], mu);
      sq[tk][i] = __fmul_rn(d, d);
    }
  }
  __syncthreads();
  if (t < 4) {
    float var = __fdiv_rn(pw1024_simd(sq[t]), 1024.0f);
    invbuf[t] = __fdiv_rn(1.0f, __fsqrt_rn(__fadd_rn(var, 1e-5f)));
  }
  __syncthreads();
  for (int tk = 0; tk < 4; ++tk) {
    const float mu = mubuf[tk], inv = invbuf[tk];
    for (int i = t; i < 1024; i += 256) {
      float d = __fsub_rn(xr[tk][i], mu);
      float v = __fadd_rn(__fmul_rn(__fmul_rn(d, inv), gb[i]), bb[i]);
      xr[tk][i] = v;
      xn[(size_t)(tok0 + tk) * H + i] = v;
    }
  }
  __syncthreads();
  if (t < 8) {
    const int tk = t >> 1, n = t & 1;
    const float* w = top_w + n * H;
    float tot = 0.f;
    for (int c0 = 0; c0 < 1024; c0 += KC) {
      const int ce = (c0 + KC < 1024) ? c0 + KC : 1024;
      float a = 0.f;
      for (int d = c0; d < ce; ++d) a = __fmaf_rn(xr[tk][d], w[d], a);
      tot = (c0 == 0) ? a : __fadd_rn(tot, a);
    }
    lbuf[tk][n] = __fadd_rn(tot, top_b[n]);
  }
  __syncthreads();
  if (t < 4) {
    float l0 = lbuf[t][0], l1 = lbuf[t][1];
    float mx = fmaxf(l0, l1);
    float e0 = np_expf(__fsub_rn(l0, mx));
    float e1 = np_expf(__fsub_rn(l1, mx));
    float sf = __fadd_rn(e0, e1);
    topp[(tok0 + t) * 2 + 0] = __fdiv_rn(e0, sf);
    topp[(tok0 + t) * 2 + 1] = __fdiv_rn(e1, sf);
  }
}

// ---- NT GEMM f32, sgemm-emulating: FMA ascending k within KC chunks ----
__global__ __launch_bounds__(256) void gemm_nt_kernel(
    const float* __restrict__ A, const float* __restrict__ B,
    const float* __restrict__ bias, float* __restrict__ C, int M, int N,
    int K) {
  __shared__ float As[16][68];
  __shared__ float Bs[16][68];
  const int t = threadIdx.x;
  const int m0 = blockIdx.y * 64, n0 = blockIdx.x * 64;
  const int lr = t >> 2;
  const int lc = (t & 3) << 2;
  const int ty = t >> 4, tx = t & 15;
  const float* Ap = A + (size_t)(m0 + lr) * K + lc;
  const float* Bp = B + (size_t)(n0 + lr) * K + lc;
  float accT[4][4] = {};
  for (int c0 = 0; c0 < K; c0 += KC) {
    const int ce = (c0 + KC < K) ? c0 + KC : K;
    float acc[4][4] = {};
    for (int k0 = c0; k0 < ce; k0 += 16) {
      float4 av = *(const float4*)(Ap + k0);
      float4 bv = *(const float4*)(Bp + k0);
      __syncthreads();
      As[lc + 0][lr] = av.x;
      As[lc + 1][lr] = av.y;
      As[lc + 2][lr] = av.z;
      As[lc + 3][lr] = av.w;
      Bs[lc + 0][lr] = bv.x;
      Bs[lc + 1][lr] = bv.y;
      Bs[lc + 2][lr] = bv.z;
      Bs[lc + 3][lr] = bv.w;
      __syncthreads();
#pragma unroll
      for (int kk = 0; kk < 16; ++kk) {
        float4 a4 = *(const float4*)&As[kk][ty * 4];
        float4 b4 = *(const float4*)&Bs[kk][tx * 4];
        float a[4] = {a4.x, a4.y, a4.z, a4.w};
        float b[4] = {b4.x, b4.y, b4.z, b4.w};
#pragma unroll
        for (int i = 0; i < 4; ++i)
#pragma unroll
          for (int j = 0; j < 4; ++j)
            acc[i][j] = __fmaf_rn(a[i], b[j], acc[i][j]);
      }
    }
#pragma unroll
    for (int i = 0; i < 4; ++i)
#pragma unroll
      for (int j = 0; j < 4; ++j)
        accT[i][j] = (c0 == 0) ? acc[i][j] : __fadd_rn(accT[i][j], acc[i][j]);
  }
  float4 bb = *(const float4*)(bias + n0 + tx * 4);
  float bias4[4] = {bb.x, bb.y, bb.z, bb.w};
#pragma unroll
  for (int i = 0; i < 4; ++i) {
    float* co = C + (size_t)(m0 + ty * 4 + i) * N + n0 + tx * 4;
#pragma unroll
    for (int j = 0; j < 4; ++j) co[j] = __fadd_rn(accT[i][j], bias4[j]);
  }
}

// ---------------- attention v5: R21 + padded kv stride (conflict fix) -------
__global__ __launch_bounds__(256, 2) void attn_kernel(
    const float* __restrict__ qkv, float* __restrict__ attn_o) {
  __shared__ float p[AR][2048];
  __shared__ float kv[64][KVP];
  __shared__ float qbuf[AR][128];
  __shared__ float leafbuf[AR][16];
  __shared__ float mxbuf[AR], denbuf[AR];
  const int t = threadIdx.x;
  const int q0 = blockIdx.x * AR;
  const int slab = blockIdx.y;
  const int b = slab >> 3, h = slab & 7;
  const size_t tokbase = (size_t)b * SEQ;
  const size_t base = tokbase * 3072 + (size_t)h * 128;
  const float SQ128 = __fsqrt_rn(128.0f);
  const int w = t >> 6;  // wave 0..3 == q-row
  const int ln = t & 63;

  // stage Q (4 rows x 128)
  if (t < 128) {
    const int r = t >> 5, c4 = (t & 31) * 4;
    *(float4*)&qbuf[r][c4] =
        *(const float4*)(qkv + base + (size_t)(q0 + r) * 3072 + c4);
  }

  // ---- Phase A: scores, 32 K-tiles of 64 rows ----
  for (int kc = 0; kc < 32; ++kc) {
    __syncthreads();
    {
      const int row = t >> 2, seg = (t & 3) * 32;
      const float* src =
          qkv + base + 1024 + (size_t)(kc * 64 + row) * 3072 + seg;
#pragma unroll
      for (int i = 0; i < 8; ++i)
        *(float4*)&kv[row][seg + i * 4] = *(const float4*)(src + i * 4);
    }
    __syncthreads();
    const float* qb = qbuf[w];
    const float* kr = kv[ln];
    float L0 = 0.f, L1 = 0.f, L2 = 0.f, L3 = 0.f;
    for (int d = 0; d < 128; d += 4) {
      L0 = __fadd_rn(L0, __fmul_rn(qb[d + 0], kr[d + 0]));
      L1 = __fadd_rn(L1, __fmul_rn(qb[d + 1], kr[d + 1]));
      L2 = __fadd_rn(L2, __fmul_rn(qb[d + 2], kr[d + 2]));
      L3 = __fadd_rn(L3, __fmul_rn(qb[d + 3], kr[d + 3]));
    }
    float acc = __fadd_rn(__fadd_rn(L0, L1), __fadd_rn(L2, L3));
    p[w][kc * 64 + ln] = __fdiv_rn(acc, SQ128);
  }
  __syncthreads();

  // ---- Phase B: softmax per row, 1 wave per row ----
  {
    float m = -INFINITY;
    for (int c = ln; c < 2048; c += 64) m = fmaxf(m, p[w][c]);
#pragma unroll
    for (int msk = 1; msk < 64; msk <<= 1) m = fmaxf(m, __shfl_xor(m, msk));
    if (ln == 0) mxbuf[w] = m;
  }
  __syncthreads();
  {
    const float mx = mxbuf[w];
    for (int c = ln; c < 2048; c += 64)
      p[w][c] = np_expf(__fsub_rn(p[w][c], mx));
  }
  __syncthreads();
  // denominator: 16 pw128 leaves per row (exact numpy pairwise tree)
  if (t < 64) {
    const int row = t >> 4, leaf = t & 15;
    leafbuf[row][leaf] = pw128_simd(&p[row][leaf * 128]);
  }
  __syncthreads();
  if (t < AR) {
    const float* B = leafbuf[t];
    float t1 =
        __fadd_rn(__fadd_rn(__fadd_rn(B[0], B[1]), __fadd_rn(B[2], B[3])),
                  __fadd_rn(__fadd_rn(B[4], B[5]), __fadd_rn(B[6], B[7])));
    float t2 = __fadd_rn(
        __fadd_rn(__fadd_rn(B[8], B[9]), __fadd_rn(B[10], B[11])),
        __fadd_rn(__fadd_rn(B[12], B[13]), __fadd_rn(B[14], B[15])));
    denbuf[t] = __fadd_rn(t1, t2);
  }
  __syncthreads();
  {
    const float den = denbuf[w];
    for (int c = ln; c < 2048; c += 64) p[w][c] = __fdiv_rn(p[w][c], den);
  }

  // ---- Phase C: PV, 32 V-tiles of 64 rows ----
  const int dd = t & 127, rh = t >> 7;  // rh 0..1
  const int r0 = rh * 2, r1 = rh * 2 + 1;
  float o0 = 0.f, o1 = 0.f;
  for (int vc = 0; vc < 32; ++vc) {
    __syncthreads();
    {
      const int row = t >> 2, seg = (t & 3) * 32;
      const float* src =
          qkv + base + 2048 + (size_t)(vc * 64 + row) * 3072 + seg;
#pragma unroll
      for (int i = 0; i < 8; ++i)
        *(float4*)&kv[row][seg + i * 4] = *(const float4*)(src + i * 4);
    }
    __syncthreads();
    const int colb = vc * 64;
    for (int kl4 = 0; kl4 < 16; ++kl4) {
      float4 pa = *(const float4*)&p[r0][colb + kl4 * 4];
      float4 pb = *(const float4*)&p[r1][colb + kl4 * 4];
      float v0 = kv[kl4 * 4 + 0][dd];
      float v1 = kv[kl4 * 4 + 1][dd];
      float v2 = kv[kl4 * 4 + 2][dd];
      float v3 = kv[kl4 * 4 + 3][dd];
      o0 = __fadd_rn(o0, __fmul_rn(pa.x, v0));
      o0 = __fadd_rn(o0, __fmul_rn(pa.y, v1));
      o0 = __fadd_rn(o0, __fmul_rn(pa.z, v2));
      o0 = __fadd_rn(o0, __fmul_rn(pa.w, v3));
      o1 = __fadd_rn(o1, __fmul_rn(pb.x, v0));
      o1 = __fadd_rn(o1, __fmul_rn(pb.y, v1));
      o1 = __fadd_rn(o1, __fmul_rn(pb.z, v2));
      o1 = __fadd_rn(o1, __fmul_rn(pb.w, v3));
    }
  }
  attn_o[(tokbase + q0 + r0) * (size_t)H + h * 128 + dd] = o0;
  attn_o[(tokbase + q0 + r1) * (size_t)H + h * 128 + dd] = o1;
}

// ---------------- expert router with np.argsort top-k ----------------
__global__ __launch_bounds__(64) void router_kernel(
    const float* __restrict__ attn_f, const float* __restrict__ hier_w,
    const float* __restrict__ hier_b, double* __restrict__ ppe,
    double* __restrict__ hb, float* __restrict__ topp_and_idx,
    float* __restrict__ out_p) {
  __shared__ float nums[64];
  __shared__ float pv[64];
  const int tok = blockIdx.x;
  const int e = threadIdx.x;
  const float tp0 = topp_and_idx[tok * 2 + 0];
  const float tp1 = topp_and_idx[tok * 2 + 1];
  const float* a = attn_f + (size_t)tok * H;
  const float* w = hier_w + (size_t)e * H;
  float L0 = 0.f, L1 = 0.f, L2 = 0.f, L3 = 0.f;
  for (int d = 0; d < 1024; d += 4) {
    L0 = __fadd_rn(L0, __fmul_rn(a[d + 0], w[d + 0]));
    L1 = __fadd_rn(L1, __fmul_rn(a[d + 1], w[d + 1]));
    L2 = __fadd_rn(L2, __fmul_rn(a[d + 2], w[d + 2]));
    L3 = __fadd_rn(L3, __fmul_rn(a[d + 3], w[d + 3]));
  }
  float acc = __fadd_rn(__fadd_rn(L0, L1), __fadd_rn(L2, L3));
  const float hl = __fadd_rn(acc, hier_b[e]);
  const float el = __fmul_rn(hl, e < 32 ? tp0 : tp1);
  float mx = el;
#pragma unroll
  for (int msk = 1; msk < 64; msk <<= 1) mx = fmaxf(mx, __shfl_xor(mx, msk));
  const float num = np_expf(__fsub_rn(el, mx));
  nums[e] = num;
  __syncthreads();
  const float s32 = pw64_simd(nums);
  const float p = __fdiv_rn(num, s32);
  atomicAdd(&ppe[e], (double)p);
  pv[e] = p;
  __syncthreads();
  if (e == 0) {
    int idxb[64];
    for (int i = 0; i < 64; ++i) idxb[i] = i;
    np_aquicksort64(pv, idxb);
    const int i1 = idxb[63], i2 = idxb[62];
    const float v1 = pv[i1], v2 = pv[i2];
    atomicAdd(&hb[0], (double)tp0);
    atomicAdd(&hb[1], (double)tp1);
    topp_and_idx[tok * 2 + 0] = (float)i1;
    topp_and_idx[tok * 2 + 1] = (float)i2;
    const float s2 = __fadd_rn(v1, v2);
    out_p[tok * 2 + 0] = __fdiv_rn(v1, s2);
    out_p[tok * 2 + 1] = __fdiv_rn(v2, s2);
  }
}

// ---------------- aux loss ----------------
__global__ __launch_bounds__(64) void final_kernel(
    const double* __restrict__ ppe, const double* __restrict__ hb,
    float* __restrict__ out_aux) {
  const int e = threadIdx.x;
  double pm = ppe[e] * (1.0 / NTOK);
  double lb = pm * log(pm * 64. + 1e-9);
  lb = wave_sum64d(lb);
  double hl = 0.;
  if (e < 2) {
    double hm = hb[e] * (1.0 / NTOK);
    hl = hm * log(hm * 2. + 1e-9);
  }
  hl = wave_sum64d(hl);
  if (e == 0) out_aux[0] = (float)(lb + 0.1 * hl);
}

extern "C" void kernel_launch(void* const* d_in, const int* in_sizes, int n_in,
                              void* d_out, int out_size, void* d_ws,
                              size_t ws_size, hipStream_t stream) {
  const float* x = (const float*)d_in[0];
  const float* ln_g = (const float*)d_in[1];
  const float* ln_b = (const float*)d_in[2];
  const float* in_w = (const float*)d_in[3];
  const float* in_b = (const float*)d_in[4];
  const float* out_w = (const float*)d_in[5];
  const float* out_b = (const float*)d_in[6];
  const float* top_w = (const float*)d_in[7];
  const float* top_b = (const float*)d_in[8];
  const float* hier_w = (const float*)d_in[9];
  const float* hier_b = (const float*)d_in[10];
  float* ws = (float*)d_ws;
  float* xn = ws;
  float* attn_o = ws;
  float* qkv = ws + 4194304;
  float* attn_f = ws + 4194304;
  double* ppe = (double*)(ws + 8388608);
  double* hb = ppe + 64;
  float* out = (float*)d_out;
  float* topp = out;

  hipLaunchKernelGGL(ln_top_kernel, dim3(NTOK / 4), dim3(256), 0, stream, x,
                     ln_g, ln_b, top_w, top_b, xn, topp);
  hipLaunchKernelGGL(gemm_nt_kernel, dim3(48, 64), dim3(256), 0, stream, xn,
                     in_w, in_b, qkv, 4096, 3072, 1024);
  hipLaunchKernelGGL(attn_kernel, dim3(SEQ / AR, 16), dim3(256), 0, stream,
                     qkv, attn_o);
  hipLaunchKernelGGL(gemm_nt_kernel, dim3(16, 64), dim3(256), 0, stream,
                     attn_o, out_w, out_b, attn_f, 4096, 1024, 1024);
  hipLaunchKernelGGL(zero_kernel, dim3(1), dim3(256), 0, stream,
                     (float*)(void*)ppe, 132);
  hipLaunchKernelGGL(router_kernel, dim3(NTOK), dim3(64), 0, stream, attn_f,
                     hier_w, hier_b, ppe, hb, topp, out + 2 * NTOK);
  hipLaunchKernelGGL(final_kernel, dim3(1), dim3(64), 0, stream, ppe, hb,
                     out + 4 * NTOK);
}

// Round 23
// 3081.291 us; speedup vs baseline: 1.4141x; 1.4141x over previous
//
#include <hip/hip_runtime.h>
#include <hip/hip_bf16.h>
#include <math.h>

#define H 1024
#define SEQ 2048
#define NTOK 4096
#define NE 64
#define AR 8    // q-rows per attn block (1 per wave, 512 threads)
#define KVP 132 // K/V row stride (16B-aligned rows for b128 LDS reads)
#define KC 384  // OpenBLAS sgemm k-blocking (HASWELL/ZEN SGEMM_DEFAULT_Q)

// ---------------- numpy-emulation helpers ----------------
// numpy f32 exp: Cephes-based FMA SIMD kernel (loops_exponent_log)
__device__ __forceinline__ float np_expf(float x) {
  const float LOG2EF = 1.44269504088896341f;
  const float C1 = 0.693359375f;
  const float C2 = -2.12194440e-4f;
  float q = rintf(__fmul_rn(x, LOG2EF));
  float r = __fmaf_rn(q, -C1, x);
  r = __fmaf_rn(q, -C2, r);
  float p = 1.9875691500E-4f;
  p = __fmaf_rn(p, r, 1.3981999507E-3f);
  p = __fmaf_rn(p, r, 8.3334519073E-3f);
  p = __fmaf_rn(p, r, 4.1665795894E-2f);
  p = __fmaf_rn(p, r, 1.6666665459E-1f);
  p = __fmaf_rn(p, r, 5.0000001201E-1f);
  float r2 = __fmul_rn(r, r);
  float y = __fmaf_rn(p, r2, r);
  y = __fadd_rn(y, 1.0f);
  y = ldexpf(y, (int)q);
  if (x < -87.3365f) y = 0.0f;
  return y;
}

// numpy pairwise_sum SIMD block: 4 vector accs x 4 lanes
__device__ __forceinline__ float pw128_simd(const float* a) {
  float r[16];
#pragma unroll
  for (int i = 0; i < 16; ++i) r[i] = a[i];
#pragma unroll
  for (int m = 1; m < 8; ++m)
#pragma unroll
    for (int i = 0; i < 16; ++i) r[i] = __fadd_rn(r[i], a[m * 16 + i]);
  float V[4];
#pragma unroll
  for (int l = 0; l < 4; ++l)
    V[l] = __fadd_rn(__fadd_rn(r[l], r[4 + l]), __fadd_rn(r[8 + l], r[12 + l]));
  return __fadd_rn(__fadd_rn(V[0], V[2]), __fadd_rn(V[1], V[3]));
}
__device__ __forceinline__ float pw64_simd(const float* a) {
  float r[16];
#pragma unroll
  for (int i = 0; i < 16; ++i) r[i] = a[i];
#pragma unroll
  for (int m = 1; m < 4; ++m)
#pragma unroll
    for (int i = 0; i < 16; ++i) r[i] = __fadd_rn(r[i], a[m * 16 + i]);
  float V[4];
#pragma unroll
  for (int l = 0; l < 4; ++l)
    V[l] = __fadd_rn(__fadd_rn(r[l], r[4 + l]), __fadd_rn(r[8 + l], r[12 + l]));
  return __fadd_rn(__fadd_rn(V[0], V[2]), __fadd_rn(V[1], V[3]));
}
__device__ __forceinline__ float pw1024_simd(const float* a) {
  float B[8];
#pragma unroll
  for (int i = 0; i < 8; ++i) B[i] = pw128_simd(a + i * 128);
  return __fadd_rn(__fadd_rn(__fadd_rn(B[0], B[1]), __fadd_rn(B[2], B[3])),
                   __fadd_rn(__fadd_rn(B[4], B[5]), __fadd_rn(B[6], B[7])));
}
__device__ __forceinline__ double wave_sum64d(double v) {
#pragma unroll
  for (int m = 32; m >= 1; m >>= 1) v += __shfl_xor(v, m);
  return v;
}

// ---------------- numpy argsort (introsort) — verbatim port ----------------
__device__ void np_aheapsort(const float* v, int* tosort, int off, int n) {
  int* a = tosort + off - 1;  // 1-based
  for (int l = n >> 1; l > 0; --l) {
    int tmp = a[l];
    int i = l, j = l << 1;
    while (j <= n) {
      if (j < n && v[a[j]] < v[a[j + 1]]) j += 1;
      if (v[tmp] < v[a[j]]) {
        a[i] = a[j];
        i = j;
        j += j;
      } else
        break;
    }
    a[i] = tmp;
  }
  for (int m = n; m > 1;) {
    int tmp = a[m];
    a[m] = a[1];
    m -= 1;
    int i = 1, j = 2;
    while (j <= m) {
      if (j < m && v[a[j]] < v[a[j + 1]]) j++;
      if (v[tmp] < v[a[j]]) {
        a[i] = a[j];
        i = j;
        j += j;
      } else
        break;
    }
    a[i] = tmp;
  }
}

__device__ void np_aquicksort64(const float* v, int* t) {
  int stk[40];
  int sp = 0;
  int pl = 0, pr = 63;
  int depth_limit = 12;
  for (;;) {
    while ((pr - pl) > 15) {
      if (depth_limit-- < 0) {
        np_aheapsort(v, t, pl, pr - pl + 1);
        goto stack_pop;
      }
      int pm = pl + ((pr - pl) >> 1);
      if (v[t[pm]] < v[t[pl]]) {
        int x = t[pm];
        t[pm] = t[pl];
        t[pl] = x;
      }
      if (v[t[pr]] < v[t[pm]]) {
        int x = t[pr];
        t[pr] = t[pm];
        t[pm] = x;
      }
      if (v[t[pm]] < v[t[pl]]) {
        int x = t[pm];
        t[pm] = t[pl];
        t[pl] = x;
      }
      float vp = v[t[pm]];
      int pi = pl;
      int pj = pr - 1;
      {
        int x = t[pm];
        t[pm] = t[pj];
        t[pj] = x;
      }
      for (;;) {
        do ++pi;
        while (v[t[pi]] < vp);
        do --pj;
        while (vp < v[t[pj]]);
        if (pi >= pj) break;
        int x = t[pi];
        t[pi] = t[pj];
        t[pj] = x;
      }
      {
        int pk = pr - 1;
        int x = t[pi];
        t[pi] = t[pk];
        t[pk] = x;
      }
      if (pi - pl < pr - pi) {
        stk[sp++] = pi + 1;
        stk[sp++] = pr;
        pr = pi - 1;
      } else {
        stk[sp++] = pl;
        stk[sp++] = pi - 1;
        pl = pi + 1;
      }
    }
    for (int pi2 = pl + 1; pi2 <= pr; ++pi2) {
      int vi = t[pi2];
      float vpp = v[vi];
      int pj2 = pi2, pk2 = pi2 - 1;
      while (pj2 > pl && vpp < v[t[pk2]]) {
        t[pj2--] = t[pk2--];
      }
      t[pj2] = vi;
    }
  stack_pop:
    if (sp == 0) break;
    pr = stk[--sp];
    pl = stk[--sp];
  }
}

__global__ void zero_kernel(float* p, int n) {
  int i = blockIdx.x * blockDim.x + threadIdx.x;
  if (i < n) p[i] = 0.f;
}

// ---------------- LayerNorm + top router ----------------
__global__ __launch_bounds__(256) void ln_top_kernel(
    const float* __restrict__ x, const float* __restrict__ g,
    const float* __restrict__ be, const float* __restrict__ top_w,
    const float* __restrict__ top_b, float* __restrict__ xn,
    float* __restrict__ topp) {
  __shared__ float xr[4][1024];
  __shared__ float sq[4][1024];
  __shared__ float gb[1024], bb[1024];
  __shared__ float mubuf[4], invbuf[4];
  __shared__ float lbuf[4][2];
  const int t = threadIdx.x;
  const int tok0 = blockIdx.x * 4;
  for (int i = t; i < 1024; i += 256) {
    gb[i] = g[i];
    bb[i] = be[i];
  }
  for (int tk = 0; tk < 4; ++tk)
    for (int i = t; i < 1024; i += 256)
      xr[tk][i] = x[(size_t)(tok0 + tk) * H + i];
  __syncthreads();
  if (t < 4) mubuf[t] = __fdiv_rn(pw1024_simd(xr[t]), 1024.0f);
  __syncthreads();
  for (int tk = 0; tk < 4; ++tk) {
    const float mu = mubuf[tk];
    for (int i = t; i < 1024; i += 256) {
      float d = __fsub_rn(xr[tk][i], mu);
      sq[tk][i] = __fmul_rn(d, d);
    }
  }
  __syncthreads();
  if (t < 4) {
    float var = __fdiv_rn(pw1024_simd(sq[t]), 1024.0f);
    invbuf[t] = __fdiv_rn(1.0f, __fsqrt_rn(__fadd_rn(var, 1e-5f)));
  }
  __syncthreads();
  for (int tk = 0; tk < 4; ++tk) {
    const float mu = mubuf[tk], inv = invbuf[tk];
    for (int i = t; i < 1024; i += 256) {
      float d = __fsub_rn(xr[tk][i], mu);
      float v = __fadd_rn(__fmul_rn(__fmul_rn(d, inv), gb[i]), bb[i]);
      xr[tk][i] = v;
      xn[(size_t)(tok0 + tk) * H + i] = v;
    }
  }
  __syncthreads();
  if (t < 8) {
    const int tk = t >> 1, n = t & 1;
    const float* w = top_w + n * H;
    float tot = 0.f;
    for (int c0 = 0; c0 < 1024; c0 += KC) {
      const int ce = (c0 + KC < 1024) ? c0 + KC : 1024;
      float a = 0.f;
      for (int d = c0; d < ce; ++d) a = __fmaf_rn(xr[tk][d], w[d], a);
      tot = (c0 == 0) ? a : __fadd_rn(tot, a);
    }
    lbuf[tk][n] = __fadd_rn(tot, top_b[n]);
  }
  __syncthreads();
  if (t < 4) {
    float l0 = lbuf[t][0], l1 = lbuf[t][1];
    float mx = fmaxf(l0, l1);
    float e0 = np_expf(__fsub_rn(l0, mx));
    float e1 = np_expf(__fsub_rn(l1, mx));
    float sf = __fadd_rn(e0, e1);
    topp[(tok0 + t) * 2 + 0] = __fdiv_rn(e0, sf);
    topp[(tok0 + t) * 2 + 1] = __fdiv_rn(e1, sf);
  }
}

// ---- NT GEMM f32, sgemm-emulating: FMA ascending k within KC chunks ----
__global__ __launch_bounds__(256) void gemm_nt_kernel(
    const float* __restrict__ A, const float* __restrict__ B,
    const float* __restrict__ bias, float* __restrict__ C, int M, int N,
    int K) {
  __shared__ float As[16][68];
  __shared__ float Bs[16][68];
  const int t = threadIdx.x;
  const int m0 = blockIdx.y * 64, n0 = blockIdx.x * 64;
  const int lr = t >> 2;
  const int lc = (t & 3) << 2;
  const int ty = t >> 4, tx = t & 15;
  const float* Ap = A + (size_t)(m0 + lr) * K + lc;
  const float* Bp = B + (size_t)(n0 + lr) * K + lc;
  float accT[4][4] = {};
  for (int c0 = 0; c0 < K; c0 += KC) {
    const int ce = (c0 + KC < K) ? c0 + KC : K;
    float acc[4][4] = {};
    for (int k0 = c0; k0 < ce; k0 += 16) {
      float4 av = *(const float4*)(Ap + k0);
      float4 bv = *(const float4*)(Bp + k0);
      __syncthreads();
      As[lc + 0][lr] = av.x;
      As[lc + 1][lr] = av.y;
      As[lc + 2][lr] = av.z;
      As[lc + 3][lr] = av.w;
      Bs[lc + 0][lr] = bv.x;
      Bs[lc + 1][lr] = bv.y;
      Bs[lc + 2][lr] = bv.z;
      Bs[lc + 3][lr] = bv.w;
      __syncthreads();
#pragma unroll
      for (int kk = 0; kk < 16; ++kk) {
        float4 a4 = *(const float4*)&As[kk][ty * 4];
        float4 b4 = *(const float4*)&Bs[kk][tx * 4];
        float a[4] = {a4.x, a4.y, a4.z, a4.w};
        float b[4] = {b4.x, b4.y, b4.z, b4.w};
#pragma unroll
        for (int i = 0; i < 4; ++i)
#pragma unroll
          for (int j = 0; j < 4; ++j)
            acc[i][j] = __fmaf_rn(a[i], b[j], acc[i][j]);
      }
    }
#pragma unroll
    for (int i = 0; i < 4; ++i)
#pragma unroll
      for (int j = 0; j < 4; ++j)
        accT[i][j] = (c0 == 0) ? acc[i][j] : __fadd_rn(accT[i][j], acc[i][j]);
  }
  float4 bb = *(const float4*)(bias + n0 + tx * 4);
  float bias4[4] = {bb.x, bb.y, bb.z, bb.w};
#pragma unroll
  for (int i = 0; i < 4; ++i) {
    float* co = C + (size_t)(m0 + ty * 4 + i) * N + n0 + tx * 4;
#pragma unroll
    for (int j = 0; j < 4; ++j) co[j] = __fadd_rn(accT[i][j], bias4[j]);
  }
}

// ---------------- attention v6: 8 rows/block, Q in registers ----------------
// Bit-identical per-output chains; 512 threads (wave w = q-row w),
// LDS ~98 KB -> 1 block/CU, 2 waves/SIMD; staging traffic halved vs AR=4.
__global__ __launch_bounds__(512) void attn_kernel(
    const float* __restrict__ qkv, float* __restrict__ attn_o) {
  __shared__ float p[AR][2048];
  __shared__ float kv[64][KVP];
  __shared__ float leafbuf[AR][16];
  __shared__ float mxbuf[AR], denbuf[AR];
  const int t = threadIdx.x;
  const int q0 = blockIdx.x * AR;
  const int slab = blockIdx.y;
  const int b = slab >> 3, h = slab & 7;
  const size_t tokbase = (size_t)b * SEQ;
  const size_t base = tokbase * 3072 + (size_t)h * 128;
  const float SQ128 = __fsqrt_rn(128.0f);
  const int w = t >> 6;  // wave 0..7 == q-row
  const int ln = t & 63;

  // Q row for this wave into registers (broadcast loads, static indexing)
  float4 qreg[32];
  {
    const float* qsrc = qkv + base + (size_t)(q0 + w) * 3072;
#pragma unroll
    for (int i = 0; i < 32; ++i) qreg[i] = *(const float4*)(qsrc + i * 4);
  }

  // ---- Phase A: scores, 32 K-tiles of 64 rows ----
  for (int kc = 0; kc < 32; ++kc) {
    __syncthreads();
    {
      const int row = t >> 3, seg = (t & 7) * 16;
      const float* src =
          qkv + base + 1024 + (size_t)(kc * 64 + row) * 3072 + seg;
#pragma unroll
      for (int i = 0; i < 4; ++i)
        *(float4*)&kv[row][seg + i * 4] = *(const float4*)(src + i * 4);
    }
    __syncthreads();
    float L0 = 0.f, L1 = 0.f, L2 = 0.f, L3 = 0.f;
#pragma unroll
    for (int d4 = 0; d4 < 32; ++d4) {
      float4 k4 = *(const float4*)&kv[ln][d4 * 4];
      L0 = __fadd_rn(L0, __fmul_rn(qreg[d4].x, k4.x));
      L1 = __fadd_rn(L1, __fmul_rn(qreg[d4].y, k4.y));
      L2 = __fadd_rn(L2, __fmul_rn(qreg[d4].z, k4.z));
      L3 = __fadd_rn(L3, __fmul_rn(qreg[d4].w, k4.w));
    }
    float acc = __fadd_rn(__fadd_rn(L0, L1), __fadd_rn(L2, L3));
    p[w][kc * 64 + ln] = __fdiv_rn(acc, SQ128);
  }
  __syncthreads();

  // ---- Phase B: softmax per row, 1 wave per row ----
  {
    float m = -INFINITY;
    for (int c = ln; c < 2048; c += 64) m = fmaxf(m, p[w][c]);
#pragma unroll
    for (int msk = 1; msk < 64; msk <<= 1) m = fmaxf(m, __shfl_xor(m, msk));
    if (ln == 0) mxbuf[w] = m;
  }
  __syncthreads();
  {
    const float mx = mxbuf[w];
    for (int c = ln; c < 2048; c += 64)
      p[w][c] = np_expf(__fsub_rn(p[w][c], mx));
  }
  __syncthreads();
  // denominator: 16 pw128 leaves per row (exact numpy pairwise tree)
  if (t < 128) {
    const int row = t >> 4, leaf = t & 15;
    leafbuf[row][leaf] = pw128_simd(&p[row][leaf * 128]);
  }
  __syncthreads();
  if (t < AR) {
    const float* B = leafbuf[t];
    float t1 =
        __fadd_rn(__fadd_rn(__fadd_rn(B[0], B[1]), __fadd_rn(B[2], B[3])),
                  __fadd_rn(__fadd_rn(B[4], B[5]), __fadd_rn(B[6], B[7])));
    float t2 = __fadd_rn(
        __fadd_rn(__fadd_rn(B[8], B[9]), __fadd_rn(B[10], B[11])),
        __fadd_rn(__fadd_rn(B[12], B[13]), __fadd_rn(B[14], B[15])));
    denbuf[t] = __fadd_rn(t1, t2);
  }
  __syncthreads();
  {
    const float den = denbuf[w];
    for (int c = ln; c < 2048; c += 64) p[w][c] = __fdiv_rn(p[w][c], den);
  }

  // ---- Phase C: PV, 32 V-tiles of 64 rows ----
  const int dd = t & 127, rq = t >> 7;  // rq 0..3
  const int r0 = rq * 2, r1 = rq * 2 + 1;
  float o0 = 0.f, o1 = 0.f;
  for (int vc = 0; vc < 32; ++vc) {
    __syncthreads();
    {
      const int row = t >> 3, seg = (t & 7) * 16;
      const float* src =
          qkv + base + 2048 + (size_t)(vc * 64 + row) * 3072 + seg;
#pragma unroll
      for (int i = 0; i < 4; ++i)
        *(float4*)&kv[row][seg + i * 4] = *(const float4*)(src + i * 4);
    }
    __syncthreads();
    const int colb = vc * 64;
    for (int kl4 = 0; kl4 < 16; ++kl4) {
      float4 pa = *(const float4*)&p[r0][colb + kl4 * 4];
      float4 pb = *(const float4*)&p[r1][colb + kl4 * 4];
      float v0 = kv[kl4 * 4 + 0][dd];
      float v1 = kv[kl4 * 4 + 1][dd];
      float v2 = kv[kl4 * 4 + 2][dd];
      float v3 = kv[kl4 * 4 + 3][dd];
      o0 = __fadd_rn(o0, __fmul_rn(pa.x, v0));
      o0 = __fadd_rn(o0, __fmul_rn(pa.y, v1));
      o0 = __fadd_rn(o0, __fmul_rn(pa.z, v2));
      o0 = __fadd_rn(o0, __fmul_rn(pa.w, v3));
      o1 = __fadd_rn(o1, __fmul_rn(pb.x, v0));
      o1 = __fadd_rn(o1, __fmul_rn(pb.y, v1));
      o1 = __fadd_rn(o1, __fmul_rn(pb.z, v2));
      o1 = __fadd_rn(o1, __fmul_rn(pb.w, v3));
    }
  }
  attn_o[(tokbase + q0 + r0) * (size_t)H + h * 128 + dd] = o0;
  attn_o[(tokbase + q0 + r1) * (size_t)H + h * 128 + dd] = o1;
}

// ---------------- expert router with np.argsort top-k ----------------
__global__ __launch_bounds__(64) void router_kernel(
    const float* __restrict__ attn_f, const float* __restrict__ hier_w,
    const float* __restrict__ hier_b, double* __restrict__ ppe,
    double* __restrict__ hb, float* __restrict__ topp_and_idx,
    float* __restrict__ out_p) {
  __shared__ float nums[64];
  __shared__ float pv[64];
  const int tok = blockIdx.x;
  const int e = threadIdx.x;
  const float tp0 = topp_and_idx[tok * 2 + 0];
  const float tp1 = topp_and_idx[tok * 2 + 1];
  const float* a = attn_f + (size_t)tok * H;
  const float* w = hier_w + (size_t)e * H;
  float L0 = 0.f, L1 = 0.f, L2 = 0.f, L3 = 0.f;
  for (int d = 0; d < 1024; d += 4) {
    L0 = __fadd_rn(L0, __fmul_rn(a[d + 0], w[d + 0]));
    L1 = __fadd_rn(L1, __fmul_rn(a[d + 1], w[d + 1]));
    L2 = __fadd_rn(L2, __fmul_rn(a[d + 2], w[d + 2]));
    L3 = __fadd_rn(L3, __fmul_rn(a[d + 3], w[d + 3]));
  }
  float acc = __fadd_rn(__fadd_rn(L0, L1), __fadd_rn(L2, L3));
  const float hl = __fadd_rn(acc, hier_b[e]);
  const float el = __fmul_rn(hl, e < 32 ? tp0 : tp1);
  float mx = el;
#pragma unroll
  for (int msk = 1; msk < 64; msk <<= 1) mx = fmaxf(mx, __shfl_xor(mx, msk));
  const float num = np_expf(__fsub_rn(el, mx));
  nums[e] = num;
  __syncthreads();
  const float s32 = pw64_simd(nums);
  const float p = __fdiv_rn(num, s32);
  atomicAdd(&ppe[e], (double)p);
  pv[e] = p;
  __syncthreads();
  if (e == 0) {
    int idxb[64];
    for (int i = 0; i < 64; ++i) idxb[i] = i;
    np_aquicksort64(pv, idxb);
    const int i1 = idxb[63], i2 = idxb[62];
    const float v1 = pv[i1], v2 = pv[i2];
    atomicAdd(&hb[0], (double)tp0);
    atomicAdd(&hb[1], (double)tp1);
    topp_and_idx[tok * 2 + 0] = (float)i1;
    topp_and_idx[tok * 2 + 1] = (float)i2;
    const float s2 = __fadd_rn(v1, v2);
    out_p[tok * 2 + 0] = __fdiv_rn(v1, s2);
    out_p[tok * 2 + 1] = __fdiv_rn(v2, s2);
  }
}

// ---------------- aux loss ----------------
__global__ __launch_bounds__(64) void final_kernel(
    const double* __restrict__ ppe, const double* __restrict__ hb,
    float* __restrict__ out_aux) {
  const int e = threadIdx.x;
  double pm = ppe[e] * (1.0 / NTOK);
  double lb = pm * log(pm * 64. + 1e-9);
  lb = wave_sum64d(lb);
  double hl = 0.;
  if (e < 2) {
    double hm = hb[e] * (1.0 / NTOK);
    hl = hm * log(hm * 2. + 1e-9);
  }
  hl = wave_sum64d(hl);
  if (e == 0) out_aux[0] = (float)(lb + 0.1 * hl);
}

extern "C" void kernel_launch(void* const* d_in, const int* in_sizes, int n_in,
                              void* d_out, int out_size, void* d_ws,
                              size_t ws_size, hipStream_t stream) {
  const float* x = (const float*)d_in[0];
  const float* ln_g = (const float*)d_in[1];
  const float* ln_b = (const float*)d_in[2];
  const float* in_w = (const float*)d_in[3];
  const float* in_b = (const float*)d_in[4];
  const float* out_w = (const float*)d_in[5];
  const float* out_b = (const float*)d_in[6];
  const float* top_w = (const float*)d_in[7];
  const float* top_b = (const float*)d_in[8];
  const float* hier_w = (const float*)d_in[9];
  const float* hier_b = (const float*)d_in[10];
  float* ws = (float*)d_ws;
  float* xn = ws;
  float* attn_o = ws;
  float* qkv = ws + 4194304;
  float* attn_f = ws + 4194304;
  double* ppe = (double*)(ws + 8388608);
  double* hb = ppe + 64;
  float* out = (float*)d_out;
  float* topp = out;

  hipLaunchKernelGGL(ln_top_kernel, dim3(NTOK / 4), dim3(256), 0, stream, x,
                     ln_g, ln_b, top_w, top_b, xn, topp);
  hipLaunchKernelGGL(gemm_nt_kernel, dim3(48, 64), dim3(256), 0, stream, xn,
                     in_w, in_b, qkv, 4096, 3072, 1024);
  hipLaunchKernelGGL(attn_kernel, dim3(SEQ / AR, 16), dim3(512), 0, stream,
                     qkv, attn_o);
  hipLaunchKernelGGL(gemm_nt_kernel, dim3(16, 64), dim3(256), 0, stream,
                     attn_o, out_w, out_b, attn_f, 4096, 1024, 1024);
  hipLaunchKernelGGL(zero_kernel, dim3(1), dim3(256), 0, stream,
                     (float*)(void*)ppe, 132);
  hipLaunchKernelGGL(router_kernel, dim3(NTOK), dim3(64), 0, stream, attn_f,
                     hier_w, hier_b, ppe, hb, topp, out + 2 * NTOK);
  hipLaunchKernelGGL(final_kernel, dim3(1), dim3(64), 0, stream, ppe, hb,
                     out + 4 * NTOK);
}